// Round 4
// baseline (942.770 us; speedup 1.0000x reference)
//
#include <hip/hip_runtime.h>

#define N_NODES 100000
#define N_EDGES 1600000
#define NBUCK 391            // ceil(N_NODES / 256)
#define HBLK 128             // blocks for histogram/scatter kernels

// ---------------- K1: coarse histograms of dst>>8 and src>>8 ----------------

__global__ __launch_bounds__(256) void coarse_hist_kernel(
    const int* __restrict__ src, const int* __restrict__ dst,
    int* __restrict__ gHD, int* __restrict__ gHS) {
    __shared__ int hd[NBUCK], hs[NBUCK];
    for (int i = threadIdx.x; i < NBUCK; i += 256) { hd[i] = 0; hs[i] = 0; }
    __syncthreads();
    for (int e = blockIdx.x * 256 + threadIdx.x; e < N_EDGES; e += HBLK * 256) {
        atomicAdd(&hd[dst[e] >> 8], 1);
        atomicAdd(&hs[src[e] >> 8], 1);
    }
    __syncthreads();
    for (int i = threadIdx.x; i < NBUCK; i += 256) {
        if (hd[i]) atomicAdd(&gHD[i], hd[i]);
        if (hs[i]) atomicAdd(&gHS[i], hs[i]);
    }
}

// ---------------- K2: scan coarse bins -> bucket bases ----------------

__global__ void coarse_scan_kernel(const int* __restrict__ gHD, const int* __restrict__ gHS,
                                   int* __restrict__ dBase, int* __restrict__ sBase) {
    __shared__ int sd[512], se[512];
    int t = threadIdx.x;
    int vd = (t < NBUCK) ? gHD[t] : 0;
    int vs = (t < NBUCK) ? gHS[t] : 0;
    sd[t] = vd; se[t] = vs;
    __syncthreads();
    for (int s = 1; s < 512; s <<= 1) {
        int ud = (t >= s) ? sd[t - s] : 0;
        int us = (t >= s) ? se[t - s] : 0;
        __syncthreads();
        sd[t] += ud; se[t] += us;
        __syncthreads();
    }
    if (t < NBUCK) { dBase[t] = sd[t] - vd; sBase[t] = se[t] - vs; }
    if (t == 0) { dBase[NBUCK] = N_EDGES; sBase[NBUCK] = N_EDGES; }
}

// ---------------- K3a: scatter edges into dst-buckets ----------------

__global__ __launch_bounds__(256) void scatter_dst_kernel(
    const int* __restrict__ src, const int* __restrict__ dst,
    const int* __restrict__ dBase, int* __restrict__ dRes,
    int* __restrict__ bsrc, unsigned char* __restrict__ bdlo) {
    __shared__ int h[NBUCK];
    __shared__ int cur[NBUCK];
    for (int i = threadIdx.x; i < NBUCK; i += 256) h[i] = 0;
    __syncthreads();
    for (int e = blockIdx.x * 256 + threadIdx.x; e < N_EDGES; e += HBLK * 256)
        atomicAdd(&h[dst[e] >> 8], 1);
    __syncthreads();
    for (int i = threadIdx.x; i < NBUCK; i += 256) {
        int c = h[i];
        cur[i] = dBase[i] + (c ? atomicAdd(&dRes[i], c) : 0);
    }
    __syncthreads();
    for (int e = blockIdx.x * 256 + threadIdx.x; e < N_EDGES; e += HBLK * 256) {
        int d = dst[e];
        int p = atomicAdd(&cur[d >> 8], 1);   // LDS atomic
        bsrc[p] = src[e];
        bdlo[p] = (unsigned char)(d & 255);
    }
}

// ---------------- K3b: scatter src low-bytes into src-buckets ----------------

__global__ __launch_bounds__(256) void scatter_src_kernel(
    const int* __restrict__ src,
    const int* __restrict__ sBase, int* __restrict__ sRes,
    unsigned char* __restrict__ bslo) {
    __shared__ int h[NBUCK];
    __shared__ int cur[NBUCK];
    for (int i = threadIdx.x; i < NBUCK; i += 256) h[i] = 0;
    __syncthreads();
    for (int e = blockIdx.x * 256 + threadIdx.x; e < N_EDGES; e += HBLK * 256)
        atomicAdd(&h[src[e] >> 8], 1);
    __syncthreads();
    for (int i = threadIdx.x; i < NBUCK; i += 256) {
        int c = h[i];
        cur[i] = sBase[i] + (c ? atomicAdd(&sRes[i], c) : 0);
    }
    __syncthreads();
    for (int e = blockIdx.x * 256 + threadIdx.x; e < N_EDGES; e += HBLK * 256) {
        int s = src[e];
        int p = atomicAdd(&cur[s >> 8], 1);   // LDS atomic
        bslo[p] = (unsigned char)(s & 255);
    }
}

// ---------------- K4: fine per dst-bucket: ideg, rs, inorm, sorted src ----------------

__global__ __launch_bounds__(256) void fine_dst_kernel(
    const int* __restrict__ dBase, const unsigned char* __restrict__ bdlo,
    const int* __restrict__ bsrc, int* __restrict__ rs, float* __restrict__ inorm,
    int* __restrict__ ssrc) {
    __shared__ int hist[256], scn[256], cur[256];
    int t = threadIdx.x, b = blockIdx.x;
    int lo = dBase[b], hi = dBase[b + 1];
    hist[t] = 0;
    __syncthreads();
    for (int p = lo + t; p < hi; p += 256) atomicAdd(&hist[bdlo[p]], 1);
    __syncthreads();
    int v = hist[t];
    scn[t] = v;
    __syncthreads();
    for (int s = 1; s < 256; s <<= 1) {
        int u = (t >= s) ? scn[t - s] : 0;
        __syncthreads();
        scn[t] += u;
        __syncthreads();
    }
    int excl = scn[t] - v;
    cur[t] = lo + excl;
    int node = b * 256 + t;
    if (node < N_NODES) {
        rs[node] = lo + excl;
        inorm[node] = 1.0f / sqrtf((float)max(v, 1));
    }
    if (b == 0 && t == 0) rs[N_NODES] = N_EDGES;
    __syncthreads();
    for (int p = lo + t; p < hi; p += 256) {
        int slot = atomicAdd(&cur[bdlo[p]], 1);   // LDS atomic
        ssrc[slot] = bsrc[p];
    }
}

// ---------------- K5: fine per src-bucket: odeg -> onorm ----------------

__global__ __launch_bounds__(256) void fine_src_kernel(
    const int* __restrict__ sBase, const unsigned char* __restrict__ bslo,
    float* __restrict__ onorm) {
    __shared__ int hist[256];
    int t = threadIdx.x, b = blockIdx.x;
    int lo = sBase[b], hi = sBase[b + 1];
    hist[t] = 0;
    __syncthreads();
    for (int p = lo + t; p < hi; p += 256) atomicAdd(&hist[bslo[p]], 1);
    __syncthreads();
    int node = b * 256 + t;
    if (node < N_NODES) onorm[node] = 1.0f / sqrtf((float)max(hist[t], 1));
}

// ---------------- GEMM1: h1 = (x * out_norm) @ W1   [N,256]@[256,64] ----------------
// Scalar-pipe outer product: 16 rows per wave via s_load, lane = output column.

__global__ __launch_bounds__(256) void gemm1_kernel(
    const float* __restrict__ x, const float* __restrict__ W,
    const float* __restrict__ onorm, float* __restrict__ h, int n) {
    const int lane = threadIdx.x & 63;
    const int wid = __builtin_amdgcn_readfirstlane(threadIdx.x >> 6);
    const int rowBase = (blockIdx.x * 4 + wid) * 16;

    float acc[16];
#pragma unroll
    for (int r = 0; r < 16; ++r) acc[r] = 0.f;

    for (int kc = 0; kc < 256; kc += 4) {
        // W column slice: 4 k-values for this lane's output column
        float w0 = W[(size_t)(kc + 0) * 64 + lane];
        float w1 = W[(size_t)(kc + 1) * 64 + lane];
        float w2 = W[(size_t)(kc + 2) * 64 + lane];
        float w3 = W[(size_t)(kc + 3) * 64 + lane];
#pragma unroll
        for (int r = 0; r < 16; ++r) {
            int row = rowBase + r;
            if (row < n) {
                const float* xr = x + (size_t)row * 256 + kc;   // uniform -> s_load_dwordx4
                float a0 = xr[0], a1 = xr[1], a2 = xr[2], a3 = xr[3];
                acc[r] += a0 * w0 + a1 * w1 + a2 * w2 + a3 * w3;
            }
        }
    }
#pragma unroll
    for (int r = 0; r < 16; ++r) {
        int row = rowBase + r;
        if (row < n) {
            float s = onorm[row];   // uniform scalar load
            h[(size_t)row * 64 + lane] = acc[r] * s;
        }
    }
}

// ---------------- agg layer1: wave per node, 4 edges x 16 float4-lanes ----------------

__global__ __launch_bounds__(256) void agg64_kernel(
    const int* __restrict__ rs, const int* __restrict__ ss,
    const float* __restrict__ h, float* __restrict__ agg, int n) {
    int node = (blockIdx.x * blockDim.x + threadIdx.x) >> 6;
    if (node >= n) return;
    int lane = threadIdx.x & 63;
    int q = lane >> 4;
    int f = lane & 15;
    int beg = rs[node], end = rs[node + 1];
    float4 a0 = {0.f, 0.f, 0.f, 0.f}, a1 = {0.f, 0.f, 0.f, 0.f};
    int j = beg;
    for (; j + 8 <= end; j += 8) {
        int s0 = ss[j + q];
        int s1 = ss[j + 4 + q];
        float4 v0 = *((const float4*)(h + (size_t)s0 * 64) + f);
        float4 v1 = *((const float4*)(h + (size_t)s1 * 64) + f);
        a0.x += v0.x; a0.y += v0.y; a0.z += v0.z; a0.w += v0.w;
        a1.x += v1.x; a1.y += v1.y; a1.z += v1.z; a1.w += v1.w;
    }
    for (; j + 4 <= end; j += 4) {
        int s0 = ss[j + q];
        float4 v0 = *((const float4*)(h + (size_t)s0 * 64) + f);
        a0.x += v0.x; a0.y += v0.y; a0.z += v0.z; a0.w += v0.w;
    }
    if (j + q < end) {
        int s0 = ss[j + q];
        float4 v0 = *((const float4*)(h + (size_t)s0 * 64) + f);
        a0.x += v0.x; a0.y += v0.y; a0.z += v0.z; a0.w += v0.w;
    }
    a0.x += a1.x; a0.y += a1.y; a0.z += a1.z; a0.w += a1.w;
    a0.x += __shfl_xor(a0.x, 16); a0.y += __shfl_xor(a0.y, 16);
    a0.z += __shfl_xor(a0.z, 16); a0.w += __shfl_xor(a0.w, 16);
    a0.x += __shfl_xor(a0.x, 32); a0.y += __shfl_xor(a0.y, 32);
    a0.z += __shfl_xor(a0.z, 32); a0.w += __shfl_xor(a0.w, 32);
    if (q == 0) ((float4*)(agg + (size_t)node * 64))[f] = a0;
}

// ---------------- GEMM2: h2 = ((agg*in_norm + b1) * out_norm) @ W2  [N,64]@[64,40] ----
// Scalar-pipe outer product: 8 rows per wave via s_load, W2 column in VGPRs.
// h2[row] = s12*(agg[row] @ W2) + so*(b1 @ W2), s12 = inorm*onorm, so = onorm.

__global__ __launch_bounds__(256) void gemm2_kernel(
    const float* __restrict__ agg, const float* __restrict__ W2,
    const float* __restrict__ b1, const float* __restrict__ inorm,
    const float* __restrict__ onorm, float* __restrict__ h2, int n) {
    const int lane = threadIdx.x & 63;
    const int wid = __builtin_amdgcn_readfirstlane(threadIdx.x >> 6);
    const int rowBase = (blockIdx.x * 4 + wid) * 8;
    const int cl = lane < 40 ? lane : 39;   // clamp idle lanes into bounds

    float w[64];
#pragma unroll
    for (int k = 0; k < 64; ++k) w[k] = W2[k * 40 + cl];

    float c2 = 0.f;
#pragma unroll
    for (int k = 0; k < 64; ++k) c2 += b1[k] * w[k];   // b1 uniform -> scalar

#pragma unroll
    for (int r = 0; r < 8; ++r) {
        int row = rowBase + r;
        if (row < n) {
            const float* ar = agg + (size_t)row * 64;   // uniform -> s_load
            float acc = 0.f;
#pragma unroll
            for (int k = 0; k < 64; ++k) acc += ar[k] * w[k];
            float so = onorm[row];
            float s12 = inorm[row] * so;
            if (lane < 40) h2[(size_t)row * 40 + lane] = acc * s12 + so * c2;
        }
    }
}

// ---------------- agg layer2 + epilogue: out = agg2 * in_norm + b2 ----------------

__global__ __launch_bounds__(256) void agg40_kernel(
    const int* __restrict__ rs, const int* __restrict__ ss,
    const float* __restrict__ h2, const float* __restrict__ inorm,
    const float* __restrict__ b2, float* __restrict__ out, int n) {
    int node = (blockIdx.x * blockDim.x + threadIdx.x) >> 6;
    if (node >= n) return;
    int lane = threadIdx.x & 63;
    int q = lane >> 4;
    int f = lane & 15;
    bool act = (f < 10);
    int beg = rs[node], end = rs[node + 1];
    float4 a0 = {0.f, 0.f, 0.f, 0.f}, a1 = {0.f, 0.f, 0.f, 0.f};
    int j = beg;
    for (; j + 8 <= end; j += 8) {
        int s0 = ss[j + q];
        int s1 = ss[j + 4 + q];
        if (act) {
            float4 v0 = *((const float4*)(h2 + (size_t)s0 * 40) + f);
            float4 v1 = *((const float4*)(h2 + (size_t)s1 * 40) + f);
            a0.x += v0.x; a0.y += v0.y; a0.z += v0.z; a0.w += v0.w;
            a1.x += v1.x; a1.y += v1.y; a1.z += v1.z; a1.w += v1.w;
        }
    }
    for (; j + 4 <= end; j += 4) {
        int s0 = ss[j + q];
        if (act) {
            float4 v0 = *((const float4*)(h2 + (size_t)s0 * 40) + f);
            a0.x += v0.x; a0.y += v0.y; a0.z += v0.z; a0.w += v0.w;
        }
    }
    if (j + q < end && act) {
        int s0 = ss[j + q];
        float4 v0 = *((const float4*)(h2 + (size_t)s0 * 40) + f);
        a0.x += v0.x; a0.y += v0.y; a0.z += v0.z; a0.w += v0.w;
    }
    a0.x += a1.x; a0.y += a1.y; a0.z += a1.z; a0.w += a1.w;
    a0.x += __shfl_xor(a0.x, 16); a0.y += __shfl_xor(a0.y, 16);
    a0.z += __shfl_xor(a0.z, 16); a0.w += __shfl_xor(a0.w, 16);
    a0.x += __shfl_xor(a0.x, 32); a0.y += __shfl_xor(a0.y, 32);
    a0.z += __shfl_xor(a0.z, 32); a0.w += __shfl_xor(a0.w, 32);
    if (q == 0 && act) {
        float s = inorm[node];
        float4 vb = ((const float4*)b2)[f];
        float4 r;
        r.x = a0.x * s + vb.x; r.y = a0.y * s + vb.y;
        r.z = a0.z * s + vb.z; r.w = a0.w * s + vb.w;
        ((float4*)(out + (size_t)node * 40))[f] = r;
    }
}

extern "C" void kernel_launch(void* const* d_in, const int* in_sizes, int n_in,
                              void* d_out, int out_size, void* d_ws, size_t ws_size,
                              hipStream_t stream) {
    const float* x  = (const float*)d_in[0];
    const int* src  = (const int*)d_in[1];
    const int* dst  = (const int*)d_in[2];
    const float* W1 = (const float*)d_in[3];
    const float* b1 = (const float*)d_in[4];
    const float* W2 = (const float*)d_in[5];
    const float* b2 = (const float*)d_in[6];
    float* out = (float*)d_out;

    char* wsb = (char*)d_ws;
    size_t off = 0;
    auto alloc = [&](size_t bytes) { char* p = wsb + off; off += (bytes + 255) & ~size_t(255); return p; };

    int*   zeroed = (int*)  alloc(4 * NBUCK * 4);        // gHD | gHS | dRes | sRes
    int*   gHD    = zeroed;
    int*   gHS    = zeroed + NBUCK;
    int*   dRes   = zeroed + 2 * NBUCK;
    int*   sRes   = zeroed + 3 * NBUCK;
    int*   dBase  = (int*)  alloc((NBUCK + 1) * 4);
    int*   sBase  = (int*)  alloc((NBUCK + 1) * 4);
    float* onorm  = (float*)alloc(N_NODES * 4);
    float* inorm  = (float*)alloc(N_NODES * 4);
    int*   rs     = (int*)  alloc((N_NODES + 1) * 4);
    int*   ssrc   = (int*)  alloc((size_t)N_EDGES * 4);
    float* h1     = (float*)alloc((size_t)N_NODES * 64 * 4);  // reused as h2 (N*40)
    float* agg1   = (float*)alloc((size_t)N_NODES * 64 * 4);
    float* h2 = h1;
    // bucket staging arrays alias agg1 (agg1 is first written by agg64, after K4/K5)
    int* bsrc = (int*)agg1;                                     // E ints
    unsigned char* bdlo = (unsigned char*)(bsrc + N_EDGES);     // E bytes
    unsigned char* bslo = bdlo + N_EDGES;                       // E bytes

    hipMemsetAsync(zeroed, 0, 4 * NBUCK * 4, stream);

    coarse_hist_kernel<<<HBLK, 256, 0, stream>>>(src, dst, gHD, gHS);
    coarse_scan_kernel<<<1, 512, 0, stream>>>(gHD, gHS, dBase, sBase);
    scatter_dst_kernel<<<HBLK, 256, 0, stream>>>(src, dst, dBase, dRes, bsrc, bdlo);
    scatter_src_kernel<<<HBLK, 256, 0, stream>>>(src, sBase, sRes, bslo);
    fine_dst_kernel<<<NBUCK, 256, 0, stream>>>(dBase, bdlo, bsrc, rs, inorm, ssrc);
    fine_src_kernel<<<NBUCK, 256, 0, stream>>>(sBase, bslo, onorm);

    gemm1_kernel<<<(N_NODES + 63) / 64, 256, 0, stream>>>(x, W1, onorm, h1, N_NODES);

    agg64_kernel<<<(N_NODES * 64) / 256, 256, 0, stream>>>(rs, ssrc, h1, agg1, N_NODES);

    gemm2_kernel<<<(N_NODES + 31) / 32, 256, 0, stream>>>(agg1, W2, b1, inorm, onorm, h2, N_NODES);

    agg40_kernel<<<(N_NODES * 64) / 256, 256, 0, stream>>>(rs, ssrc, h2, inorm, b2, out, N_NODES);
}

// Round 5
// 457.628 us; speedup vs baseline: 2.0601x; 2.0601x over previous
//
#include <hip/hip_runtime.h>

#define N_NODES 100000
#define N_EDGES 1600000
#define NBUCK 391            // ceil(N_NODES / 256)
#define HBLK 128             // blocks for histogram/scatter kernels

// ---------------- K1: coarse histograms of dst>>8 and src>>8 ----------------

__global__ __launch_bounds__(256) void coarse_hist_kernel(
    const int* __restrict__ src, const int* __restrict__ dst,
    int* __restrict__ gHD, int* __restrict__ gHS) {
    __shared__ int hd[NBUCK], hs[NBUCK];
    for (int i = threadIdx.x; i < NBUCK; i += 256) { hd[i] = 0; hs[i] = 0; }
    __syncthreads();
    for (int e = blockIdx.x * 256 + threadIdx.x; e < N_EDGES; e += HBLK * 256) {
        atomicAdd(&hd[dst[e] >> 8], 1);
        atomicAdd(&hs[src[e] >> 8], 1);
    }
    __syncthreads();
    for (int i = threadIdx.x; i < NBUCK; i += 256) {
        if (hd[i]) atomicAdd(&gHD[i], hd[i]);
        if (hs[i]) atomicAdd(&gHS[i], hs[i]);
    }
}

// ---------------- K2: scan coarse bins -> bucket bases ----------------

__global__ void coarse_scan_kernel(const int* __restrict__ gHD, const int* __restrict__ gHS,
                                   int* __restrict__ dBase, int* __restrict__ sBase) {
    __shared__ int sd[512], se[512];
    int t = threadIdx.x;
    int vd = (t < NBUCK) ? gHD[t] : 0;
    int vs = (t < NBUCK) ? gHS[t] : 0;
    sd[t] = vd; se[t] = vs;
    __syncthreads();
    for (int s = 1; s < 512; s <<= 1) {
        int ud = (t >= s) ? sd[t - s] : 0;
        int us = (t >= s) ? se[t - s] : 0;
        __syncthreads();
        sd[t] += ud; se[t] += us;
        __syncthreads();
    }
    if (t < NBUCK) { dBase[t] = sd[t] - vd; sBase[t] = se[t] - vs; }
    if (t == 0) { dBase[NBUCK] = N_EDGES; sBase[NBUCK] = N_EDGES; }
}

// ---------------- K3a: scatter edges into dst-buckets ----------------

__global__ __launch_bounds__(256) void scatter_dst_kernel(
    const int* __restrict__ src, const int* __restrict__ dst,
    const int* __restrict__ dBase, int* __restrict__ dRes,
    int* __restrict__ bsrc, unsigned char* __restrict__ bdlo) {
    __shared__ int h[NBUCK];
    __shared__ int cur[NBUCK];
    for (int i = threadIdx.x; i < NBUCK; i += 256) h[i] = 0;
    __syncthreads();
    for (int e = blockIdx.x * 256 + threadIdx.x; e < N_EDGES; e += HBLK * 256)
        atomicAdd(&h[dst[e] >> 8], 1);
    __syncthreads();
    for (int i = threadIdx.x; i < NBUCK; i += 256) {
        int c = h[i];
        cur[i] = dBase[i] + (c ? atomicAdd(&dRes[i], c) : 0);
    }
    __syncthreads();
    for (int e = blockIdx.x * 256 + threadIdx.x; e < N_EDGES; e += HBLK * 256) {
        int d = dst[e];
        int p = atomicAdd(&cur[d >> 8], 1);   // LDS atomic
        bsrc[p] = src[e];
        bdlo[p] = (unsigned char)(d & 255);
    }
}

// ---------------- K3b: scatter src low-bytes into src-buckets ----------------

__global__ __launch_bounds__(256) void scatter_src_kernel(
    const int* __restrict__ src,
    const int* __restrict__ sBase, int* __restrict__ sRes,
    unsigned char* __restrict__ bslo) {
    __shared__ int h[NBUCK];
    __shared__ int cur[NBUCK];
    for (int i = threadIdx.x; i < NBUCK; i += 256) h[i] = 0;
    __syncthreads();
    for (int e = blockIdx.x * 256 + threadIdx.x; e < N_EDGES; e += HBLK * 256)
        atomicAdd(&h[src[e] >> 8], 1);
    __syncthreads();
    for (int i = threadIdx.x; i < NBUCK; i += 256) {
        int c = h[i];
        cur[i] = sBase[i] + (c ? atomicAdd(&sRes[i], c) : 0);
    }
    __syncthreads();
    for (int e = blockIdx.x * 256 + threadIdx.x; e < N_EDGES; e += HBLK * 256) {
        int s = src[e];
        int p = atomicAdd(&cur[s >> 8], 1);   // LDS atomic
        bslo[p] = (unsigned char)(s & 255);
    }
}

// ---------------- K4: fine per dst-bucket: ideg, rs, inorm, sorted src ----------------

__global__ __launch_bounds__(256) void fine_dst_kernel(
    const int* __restrict__ dBase, const unsigned char* __restrict__ bdlo,
    const int* __restrict__ bsrc, int* __restrict__ rs, float* __restrict__ inorm,
    int* __restrict__ ssrc) {
    __shared__ int hist[256], scn[256], cur[256];
    int t = threadIdx.x, b = blockIdx.x;
    int lo = dBase[b], hi = dBase[b + 1];
    hist[t] = 0;
    __syncthreads();
    for (int p = lo + t; p < hi; p += 256) atomicAdd(&hist[bdlo[p]], 1);
    __syncthreads();
    int v = hist[t];
    scn[t] = v;
    __syncthreads();
    for (int s = 1; s < 256; s <<= 1) {
        int u = (t >= s) ? scn[t - s] : 0;
        __syncthreads();
        scn[t] += u;
        __syncthreads();
    }
    int excl = scn[t] - v;
    cur[t] = lo + excl;
    int node = b * 256 + t;
    if (node < N_NODES) {
        rs[node] = lo + excl;
        inorm[node] = 1.0f / sqrtf((float)max(v, 1));
    }
    if (b == 0 && t == 0) rs[N_NODES] = N_EDGES;
    __syncthreads();
    for (int p = lo + t; p < hi; p += 256) {
        int slot = atomicAdd(&cur[bdlo[p]], 1);   // LDS atomic
        ssrc[slot] = bsrc[p];
    }
}

// ---------------- K5: fine per src-bucket: odeg -> onorm ----------------

__global__ __launch_bounds__(256) void fine_src_kernel(
    const int* __restrict__ sBase, const unsigned char* __restrict__ bslo,
    float* __restrict__ onorm) {
    __shared__ int hist[256];
    int t = threadIdx.x, b = blockIdx.x;
    int lo = sBase[b], hi = sBase[b + 1];
    hist[t] = 0;
    __syncthreads();
    for (int p = lo + t; p < hi; p += 256) atomicAdd(&hist[bslo[p]], 1);
    __syncthreads();
    int node = b * 256 + t;
    if (node < N_NODES) onorm[node] = 1.0f / sqrtf((float)max(hist[t], 1));
}

// ---------------- GEMM1: h1 = (x * out_norm) @ W1   [N,256]@[256,64] ----------------
// LDS-tiled, 64x64 tile, BK=16, 4x4 register micro-tile. (Scalar-pipe variant
// regressed 10x in R4: streaming 102 MB through s_load is lgkmcnt-latency-bound.)

__global__ __launch_bounds__(256) void gemm1_kernel(
    const float* __restrict__ x, const float* __restrict__ W,
    const float* __restrict__ onorm, float* __restrict__ h, int n) {
    __shared__ float As[16][64];
    __shared__ float Ws[16][64];
    const int tid = threadIdx.x;
    const int tx = tid & 15;
    const int ty = tid >> 4;
    const int rowBase = blockIdx.x * 64;

    const int lr = tid >> 2;
    const int lk = (tid & 3) * 4;
    const int lrow = rowBase + lr;
    const bool lvalid = (lrow < n);
    const float lscale = lvalid ? onorm[lrow] : 0.0f;
    const int wk = tid >> 4;
    const int wc = (tid & 15) * 4;

    float acc[4][4] = {};

    for (int k0 = 0; k0 < 256; k0 += 16) {
        float4 v = make_float4(0.f, 0.f, 0.f, 0.f);
        if (lvalid) v = *(const float4*)(x + (size_t)lrow * 256 + k0 + lk);
        As[lk + 0][lr] = v.x * lscale;
        As[lk + 1][lr] = v.y * lscale;
        As[lk + 2][lr] = v.z * lscale;
        As[lk + 3][lr] = v.w * lscale;
        *(float4*)&Ws[wk][wc] = *(const float4*)(W + (size_t)(k0 + wk) * 64 + wc);
        __syncthreads();
#pragma unroll
        for (int k = 0; k < 16; ++k) {
            float4 a = *(const float4*)&As[k][ty * 4];
            float4 b = *(const float4*)&Ws[k][tx * 4];
            float av[4] = {a.x, a.y, a.z, a.w};
            float bv[4] = {b.x, b.y, b.z, b.w};
#pragma unroll
            for (int i = 0; i < 4; ++i)
#pragma unroll
                for (int j = 0; j < 4; ++j) acc[i][j] += av[i] * bv[j];
        }
        __syncthreads();
    }
#pragma unroll
    for (int i = 0; i < 4; ++i) {
        int row = rowBase + ty * 4 + i;
        if (row < n) {
            *(float4*)(h + (size_t)row * 64 + tx * 4) =
                make_float4(acc[i][0], acc[i][1], acc[i][2], acc[i][3]);
        }
    }
}

// ---------------- agg layer1: wave per node, 4 edges x 16 float4-lanes ----------------

__global__ __launch_bounds__(256) void agg64_kernel(
    const int* __restrict__ rs, const int* __restrict__ ss,
    const float* __restrict__ h, float* __restrict__ agg, int n) {
    int node = (blockIdx.x * blockDim.x + threadIdx.x) >> 6;
    if (node >= n) return;
    int lane = threadIdx.x & 63;
    int q = lane >> 4;
    int f = lane & 15;
    int beg = rs[node], end = rs[node + 1];
    float4 a0 = {0.f, 0.f, 0.f, 0.f}, a1 = {0.f, 0.f, 0.f, 0.f};
    int j = beg;
    for (; j + 8 <= end; j += 8) {
        int s0 = ss[j + q];
        int s1 = ss[j + 4 + q];
        float4 v0 = *((const float4*)(h + (size_t)s0 * 64) + f);
        float4 v1 = *((const float4*)(h + (size_t)s1 * 64) + f);
        a0.x += v0.x; a0.y += v0.y; a0.z += v0.z; a0.w += v0.w;
        a1.x += v1.x; a1.y += v1.y; a1.z += v1.z; a1.w += v1.w;
    }
    for (; j + 4 <= end; j += 4) {
        int s0 = ss[j + q];
        float4 v0 = *((const float4*)(h + (size_t)s0 * 64) + f);
        a0.x += v0.x; a0.y += v0.y; a0.z += v0.z; a0.w += v0.w;
    }
    if (j + q < end) {
        int s0 = ss[j + q];
        float4 v0 = *((const float4*)(h + (size_t)s0 * 64) + f);
        a0.x += v0.x; a0.y += v0.y; a0.z += v0.z; a0.w += v0.w;
    }
    a0.x += a1.x; a0.y += a1.y; a0.z += a1.z; a0.w += a1.w;
    a0.x += __shfl_xor(a0.x, 16); a0.y += __shfl_xor(a0.y, 16);
    a0.z += __shfl_xor(a0.z, 16); a0.w += __shfl_xor(a0.w, 16);
    a0.x += __shfl_xor(a0.x, 32); a0.y += __shfl_xor(a0.y, 32);
    a0.z += __shfl_xor(a0.z, 32); a0.w += __shfl_xor(a0.w, 32);
    if (q == 0) ((float4*)(agg + (size_t)node * 64))[f] = a0;
}

// ---------------- GEMM2: h2 = ((agg*in_norm + b1) * out_norm) @ W2  [N,64]@[64,40] ----
// Scalar-pipe outer product (validated win in R4): 8 rows/wave via s_load,
// W2 column in 64 VGPRs -> 64 FMAs per scalar row-load burst.

__global__ __launch_bounds__(256) void gemm2_kernel(
    const float* __restrict__ agg, const float* __restrict__ W2,
    const float* __restrict__ b1, const float* __restrict__ inorm,
    const float* __restrict__ onorm, float* __restrict__ h2, int n) {
    const int lane = threadIdx.x & 63;
    const int wid = __builtin_amdgcn_readfirstlane(threadIdx.x >> 6);
    const int rowBase = (blockIdx.x * 4 + wid) * 8;
    const int cl = lane < 40 ? lane : 39;   // clamp idle lanes into bounds

    float w[64];
#pragma unroll
    for (int k = 0; k < 64; ++k) w[k] = W2[k * 40 + cl];

    float c2 = 0.f;
#pragma unroll
    for (int k = 0; k < 64; ++k) c2 += b1[k] * w[k];   // b1 uniform -> scalar

#pragma unroll
    for (int r = 0; r < 8; ++r) {
        int row = rowBase + r;
        if (row < n) {
            const float* ar = agg + (size_t)row * 64;   // uniform -> s_load
            float acc = 0.f;
#pragma unroll
            for (int k = 0; k < 64; ++k) acc += ar[k] * w[k];
            float so = onorm[row];
            float s12 = inorm[row] * so;
            if (lane < 40) h2[(size_t)row * 40 + lane] = acc * s12 + so * c2;
        }
    }
}

// ---------------- agg layer2 + epilogue: out = agg2 * in_norm + b2 ----------------

__global__ __launch_bounds__(256) void agg40_kernel(
    const int* __restrict__ rs, const int* __restrict__ ss,
    const float* __restrict__ h2, const float* __restrict__ inorm,
    const float* __restrict__ b2, float* __restrict__ out, int n) {
    int node = (blockIdx.x * blockDim.x + threadIdx.x) >> 6;
    if (node >= n) return;
    int lane = threadIdx.x & 63;
    int q = lane >> 4;
    int f = lane & 15;
    bool act = (f < 10);
    int beg = rs[node], end = rs[node + 1];
    float4 a0 = {0.f, 0.f, 0.f, 0.f}, a1 = {0.f, 0.f, 0.f, 0.f};
    int j = beg;
    for (; j + 8 <= end; j += 8) {
        int s0 = ss[j + q];
        int s1 = ss[j + 4 + q];
        if (act) {
            float4 v0 = *((const float4*)(h2 + (size_t)s0 * 40) + f);
            float4 v1 = *((const float4*)(h2 + (size_t)s1 * 40) + f);
            a0.x += v0.x; a0.y += v0.y; a0.z += v0.z; a0.w += v0.w;
            a1.x += v1.x; a1.y += v1.y; a1.z += v1.z; a1.w += v1.w;
        }
    }
    for (; j + 4 <= end; j += 4) {
        int s0 = ss[j + q];
        if (act) {
            float4 v0 = *((const float4*)(h2 + (size_t)s0 * 40) + f);
            a0.x += v0.x; a0.y += v0.y; a0.z += v0.z; a0.w += v0.w;
        }
    }
    if (j + q < end && act) {
        int s0 = ss[j + q];
        float4 v0 = *((const float4*)(h2 + (size_t)s0 * 40) + f);
        a0.x += v0.x; a0.y += v0.y; a0.z += v0.z; a0.w += v0.w;
    }
    a0.x += a1.x; a0.y += a1.y; a0.z += a1.z; a0.w += a1.w;
    a0.x += __shfl_xor(a0.x, 16); a0.y += __shfl_xor(a0.y, 16);
    a0.z += __shfl_xor(a0.z, 16); a0.w += __shfl_xor(a0.w, 16);
    a0.x += __shfl_xor(a0.x, 32); a0.y += __shfl_xor(a0.y, 32);
    a0.z += __shfl_xor(a0.z, 32); a0.w += __shfl_xor(a0.w, 32);
    if (q == 0 && act) {
        float s = inorm[node];
        float4 vb = ((const float4*)b2)[f];
        float4 r;
        r.x = a0.x * s + vb.x; r.y = a0.y * s + vb.y;
        r.z = a0.z * s + vb.z; r.w = a0.w * s + vb.w;
        ((float4*)(out + (size_t)node * 40))[f] = r;
    }
}

extern "C" void kernel_launch(void* const* d_in, const int* in_sizes, int n_in,
                              void* d_out, int out_size, void* d_ws, size_t ws_size,
                              hipStream_t stream) {
    const float* x  = (const float*)d_in[0];
    const int* src  = (const int*)d_in[1];
    const int* dst  = (const int*)d_in[2];
    const float* W1 = (const float*)d_in[3];
    const float* b1 = (const float*)d_in[4];
    const float* W2 = (const float*)d_in[5];
    const float* b2 = (const float*)d_in[6];
    float* out = (float*)d_out;

    char* wsb = (char*)d_ws;
    size_t off = 0;
    auto alloc = [&](size_t bytes) { char* p = wsb + off; off += (bytes + 255) & ~size_t(255); return p; };

    int*   zeroed = (int*)  alloc(4 * NBUCK * 4);        // gHD | gHS | dRes | sRes
    int*   gHD    = zeroed;
    int*   gHS    = zeroed + NBUCK;
    int*   dRes   = zeroed + 2 * NBUCK;
    int*   sRes   = zeroed + 3 * NBUCK;
    int*   dBase  = (int*)  alloc((NBUCK + 1) * 4);
    int*   sBase  = (int*)  alloc((NBUCK + 1) * 4);
    float* onorm  = (float*)alloc(N_NODES * 4);
    float* inorm  = (float*)alloc(N_NODES * 4);
    int*   rs     = (int*)  alloc((N_NODES + 1) * 4);
    int*   ssrc   = (int*)  alloc((size_t)N_EDGES * 4);
    float* h1     = (float*)alloc((size_t)N_NODES * 64 * 4);  // reused as h2 (N*40)
    float* agg1   = (float*)alloc((size_t)N_NODES * 64 * 4);
    float* h2 = h1;
    // bucket staging arrays alias agg1 (agg1 is first written by agg64, after K4/K5)
    int* bsrc = (int*)agg1;                                     // E ints
    unsigned char* bdlo = (unsigned char*)(bsrc + N_EDGES);     // E bytes
    unsigned char* bslo = bdlo + N_EDGES;                       // E bytes

    hipMemsetAsync(zeroed, 0, 4 * NBUCK * 4, stream);

    coarse_hist_kernel<<<HBLK, 256, 0, stream>>>(src, dst, gHD, gHS);
    coarse_scan_kernel<<<1, 512, 0, stream>>>(gHD, gHS, dBase, sBase);
    scatter_dst_kernel<<<HBLK, 256, 0, stream>>>(src, dst, dBase, dRes, bsrc, bdlo);
    scatter_src_kernel<<<HBLK, 256, 0, stream>>>(src, sBase, sRes, bslo);
    fine_dst_kernel<<<NBUCK, 256, 0, stream>>>(dBase, bdlo, bsrc, rs, inorm, ssrc);
    fine_src_kernel<<<NBUCK, 256, 0, stream>>>(sBase, bslo, onorm);

    gemm1_kernel<<<(N_NODES + 63) / 64, 256, 0, stream>>>(x, W1, onorm, h1, N_NODES);

    agg64_kernel<<<(N_NODES * 64) / 256, 256, 0, stream>>>(rs, ssrc, h1, agg1, N_NODES);

    gemm2_kernel<<<(N_NODES + 31) / 32, 256, 0, stream>>>(agg1, W2, b1, inorm, onorm, h2, N_NODES);

    agg40_kernel<<<(N_NODES * 64) / 256, 256, 0, stream>>>(rs, ssrc, h2, inorm, b2, out, N_NODES);
}

// Round 6
// 437.412 us; speedup vs baseline: 2.1553x; 1.0462x over previous
//
#include <hip/hip_runtime.h>

#define N_NODES 100000
#define N_EDGES 1600000
#define NBUCK 391            // ceil(N_NODES / 256)
#define HBLK 128             // blocks for histogram/scatter kernels
#define CAP 8192             // LDS edge-list capacity per bucket (mean 4092, sd 64)

// ---------------- K1: coarse histograms of dst>>8 and src>>8 ----------------

__global__ __launch_bounds__(256) void coarse_hist_kernel(
    const int* __restrict__ src, const int* __restrict__ dst,
    int* __restrict__ gHD, int* __restrict__ gHS) {
    __shared__ int hd[NBUCK], hs[NBUCK];
    for (int i = threadIdx.x; i < NBUCK; i += 256) { hd[i] = 0; hs[i] = 0; }
    __syncthreads();
    for (int e = blockIdx.x * 256 + threadIdx.x; e < N_EDGES; e += HBLK * 256) {
        atomicAdd(&hd[dst[e] >> 8], 1);
        atomicAdd(&hs[src[e] >> 8], 1);
    }
    __syncthreads();
    for (int i = threadIdx.x; i < NBUCK; i += 256) {
        if (hd[i]) atomicAdd(&gHD[i], hd[i]);
        if (hs[i]) atomicAdd(&gHS[i], hs[i]);
    }
}

// ---------------- K2: scan coarse bins -> bucket bases ----------------

__global__ void coarse_scan_kernel(const int* __restrict__ gHD, const int* __restrict__ gHS,
                                   int* __restrict__ dBase, int* __restrict__ sBase) {
    __shared__ int sd[512], se[512];
    int t = threadIdx.x;
    int vd = (t < NBUCK) ? gHD[t] : 0;
    int vs = (t < NBUCK) ? gHS[t] : 0;
    sd[t] = vd; se[t] = vs;
    __syncthreads();
    for (int s = 1; s < 512; s <<= 1) {
        int ud = (t >= s) ? sd[t - s] : 0;
        int us = (t >= s) ? se[t - s] : 0;
        __syncthreads();
        sd[t] += ud; se[t] += us;
        __syncthreads();
    }
    if (t < NBUCK) { dBase[t] = sd[t] - vd; sBase[t] = se[t] - vs; }
    if (t == 0) { dBase[NBUCK] = N_EDGES; sBase[NBUCK] = N_EDGES; }
}

// ---------------- K3: merged scatter into dst-buckets AND src-buckets ----------------

__global__ __launch_bounds__(256) void scatter_both_kernel(
    const int* __restrict__ src, const int* __restrict__ dst,
    const int* __restrict__ dBase, const int* __restrict__ sBase,
    int* __restrict__ dRes, int* __restrict__ sRes,
    int* __restrict__ bsrc, unsigned char* __restrict__ bdlo,
    unsigned char* __restrict__ bslo) {
    __shared__ int hd[NBUCK], hs[NBUCK], curD[NBUCK], curS[NBUCK];
    for (int i = threadIdx.x; i < NBUCK; i += 256) { hd[i] = 0; hs[i] = 0; }
    __syncthreads();
    for (int e = blockIdx.x * 256 + threadIdx.x; e < N_EDGES; e += HBLK * 256) {
        atomicAdd(&hd[dst[e] >> 8], 1);
        atomicAdd(&hs[src[e] >> 8], 1);
    }
    __syncthreads();
    for (int i = threadIdx.x; i < NBUCK; i += 256) {
        int cd = hd[i];
        curD[i] = dBase[i] + (cd ? atomicAdd(&dRes[i], cd) : 0);
        int cs = hs[i];
        curS[i] = sBase[i] + (cs ? atomicAdd(&sRes[i], cs) : 0);
    }
    __syncthreads();
    for (int e = blockIdx.x * 256 + threadIdx.x; e < N_EDGES; e += HBLK * 256) {
        int s = src[e];
        int d = dst[e];
        int pd = atomicAdd(&curD[d >> 8], 1);   // LDS atomic
        bsrc[pd] = s;
        bdlo[pd] = (unsigned char)(d & 255);
        int ps = atomicAdd(&curS[s >> 8], 1);   // LDS atomic
        bslo[ps] = (unsigned char)(s & 255);
    }
}

// ---------------- K4: fine per src-bucket: odeg -> onorm ----------------

__global__ __launch_bounds__(256) void fine_src_kernel(
    const int* __restrict__ sBase, const unsigned char* __restrict__ bslo,
    float* __restrict__ onorm) {
    __shared__ int hist[256];
    int t = threadIdx.x, b = blockIdx.x;
    int lo = sBase[b], hi = sBase[b + 1];
    hist[t] = 0;
    __syncthreads();
    for (int p = lo + t; p < hi; p += 256) atomicAdd(&hist[bslo[p]], 1);
    __syncthreads();
    int node = b * 256 + t;
    if (node < N_NODES) onorm[node] = 1.0f / sqrtf((float)max(hist[t], 1));
}

// ---------------- GEMM1: h1 = (x * out_norm) @ W1   [N,256]@[256,64] ----------------
// 128x64 tile, BK=16, 8x4 micro-tile. As[k][row] -> compute a-reads are
// 4-address quad-broadcast b128 (conflict-free); Ws padded to 68.

__global__ __launch_bounds__(256) void gemm1_kernel(
    const float* __restrict__ x, const float* __restrict__ W,
    const float* __restrict__ onorm, float* __restrict__ h, int n) {
    __shared__ float As[16][128];
    __shared__ float Ws[16][68];
    const int tid = threadIdx.x;
    const int tx = tid & 15;        // col group (4 cols)
    const int rg = tid >> 4;        // row group (8 rows)
    const int rowBase = blockIdx.x * 128;

    const int lr0 = tid >> 2;       // 0..63
    const int lkq = (tid & 3) * 4;  // 0,4,8,12
    const int wk = tid >> 4;
    const int wc = (tid & 15) * 4;

    const int row0 = rowBase + lr0;
    const int row1 = rowBase + 64 + lr0;
    const float sc0 = (row0 < n) ? onorm[row0] : 0.f;
    const float sc1 = (row1 < n) ? onorm[row1] : 0.f;

    float acc[8][4] = {};

    for (int k0 = 0; k0 < 256; k0 += 16) {
        *(float4*)&Ws[wk][wc] = *(const float4*)(W + (size_t)(k0 + wk) * 64 + wc);
        float4 v0 = make_float4(0.f, 0.f, 0.f, 0.f);
        float4 v1 = make_float4(0.f, 0.f, 0.f, 0.f);
        if (row0 < n) v0 = *(const float4*)(x + (size_t)row0 * 256 + k0 + lkq);
        if (row1 < n) v1 = *(const float4*)(x + (size_t)row1 * 256 + k0 + lkq);
        As[lkq + 0][lr0] = v0.x * sc0;
        As[lkq + 1][lr0] = v0.y * sc0;
        As[lkq + 2][lr0] = v0.z * sc0;
        As[lkq + 3][lr0] = v0.w * sc0;
        As[lkq + 0][64 + lr0] = v1.x * sc1;
        As[lkq + 1][64 + lr0] = v1.y * sc1;
        As[lkq + 2][64 + lr0] = v1.z * sc1;
        As[lkq + 3][64 + lr0] = v1.w * sc1;
        __syncthreads();
#pragma unroll
        for (int k = 0; k < 16; ++k) {
            float4 b = *(const float4*)&Ws[k][tx * 4];
            float4 a0 = *(const float4*)&As[k][rg * 8];
            float4 a1 = *(const float4*)&As[k][rg * 8 + 4];
            float av[8] = {a0.x, a0.y, a0.z, a0.w, a1.x, a1.y, a1.z, a1.w};
            float bv[4] = {b.x, b.y, b.z, b.w};
#pragma unroll
            for (int i = 0; i < 8; ++i)
#pragma unroll
                for (int j = 0; j < 4; ++j) acc[i][j] += av[i] * bv[j];
        }
        __syncthreads();
    }
#pragma unroll
    for (int i = 0; i < 8; ++i) {
        int row = rowBase + rg * 8 + i;
        if (row < n) {
            *(float4*)(h + (size_t)row * 64 + tx * 4) =
                make_float4(acc[i][0], acc[i][1], acc[i][2], acc[i][3]);
        }
    }
}

// ---------------- agg layer1 fused: in-LDS bucket sort + gather-acc + inorm ----------

__global__ __launch_bounds__(1024) void agg64_fused_kernel(
    const int* __restrict__ dBase, const int* __restrict__ bsrc,
    const unsigned char* __restrict__ bdlo, const float* __restrict__ h,
    float* __restrict__ agg, float* __restrict__ inorm) {
    __shared__ int lsrc[CAP];
    __shared__ int hist[256], scn[256], cur[256];
    const int tid = threadIdx.x;
    const int b = blockIdx.x;
    const int lo = dBase[b];
    const int hi = min(dBase[b + 1], lo + CAP);
    if (tid < 256) hist[tid] = 0;
    __syncthreads();
    for (int p = lo + tid; p < hi; p += 1024) atomicAdd(&hist[bdlo[p]], 1);
    __syncthreads();
    int v = (tid < 256) ? hist[tid] : 0;
    if (tid < 256) scn[tid] = v;
    __syncthreads();
    for (int s = 1; s < 256; s <<= 1) {
        int u = 0;
        if (tid < 256 && tid >= s) u = scn[tid - s];
        __syncthreads();
        if (tid < 256 && tid >= s) scn[tid] += u;
        __syncthreads();
    }
    if (tid < 256) {
        int excl = scn[tid] - v;
        scn[tid] = excl;
        cur[tid] = excl;
        int node = b * 256 + tid;
        if (node < N_NODES) inorm[node] = 1.0f / sqrtf((float)max(v, 1));
    }
    __syncthreads();
    for (int p = lo + tid; p < hi; p += 1024) {
        int pos = atomicAdd(&cur[bdlo[p]], 1);   // LDS atomic
        lsrc[pos] = bsrc[p];
    }
    __syncthreads();

    const int w = tid >> 6, lane = tid & 63, q = lane >> 4, f = lane & 15;
    for (int nn = w; nn < 256; nn += 16) {
        int node = b * 256 + nn;
        if (node >= N_NODES) break;
        int beg = scn[nn];
        int end = beg + hist[nn];
        float4 a0 = {0.f, 0.f, 0.f, 0.f}, a1 = {0.f, 0.f, 0.f, 0.f};
        int j = beg;
        for (; j + 8 <= end; j += 8) {
            int s0 = lsrc[j + q], s1 = lsrc[j + 4 + q];
            float4 v0 = *((const float4*)(h + (size_t)s0 * 64) + f);
            float4 v1 = *((const float4*)(h + (size_t)s1 * 64) + f);
            a0.x += v0.x; a0.y += v0.y; a0.z += v0.z; a0.w += v0.w;
            a1.x += v1.x; a1.y += v1.y; a1.z += v1.z; a1.w += v1.w;
        }
        for (; j + 4 <= end; j += 4) {
            int s0 = lsrc[j + q];
            float4 v0 = *((const float4*)(h + (size_t)s0 * 64) + f);
            a0.x += v0.x; a0.y += v0.y; a0.z += v0.z; a0.w += v0.w;
        }
        if (j + q < end) {
            int s0 = lsrc[j + q];
            float4 v0 = *((const float4*)(h + (size_t)s0 * 64) + f);
            a0.x += v0.x; a0.y += v0.y; a0.z += v0.z; a0.w += v0.w;
        }
        a0.x += a1.x; a0.y += a1.y; a0.z += a1.z; a0.w += a1.w;
        a0.x += __shfl_xor(a0.x, 16); a0.y += __shfl_xor(a0.y, 16);
        a0.z += __shfl_xor(a0.z, 16); a0.w += __shfl_xor(a0.w, 16);
        a0.x += __shfl_xor(a0.x, 32); a0.y += __shfl_xor(a0.y, 32);
        a0.z += __shfl_xor(a0.z, 32); a0.w += __shfl_xor(a0.w, 32);
        if (q == 0) ((float4*)(agg + (size_t)node * 64))[f] = a0;
    }
}

// ---------------- GEMM2: h2 = ((agg*in_norm + b1) * out_norm) @ W2  [N,64]@[64,40] ----
// Scalar-pipe outer product (validated win in R4).

__global__ __launch_bounds__(256) void gemm2_kernel(
    const float* __restrict__ agg, const float* __restrict__ W2,
    const float* __restrict__ b1, const float* __restrict__ inorm,
    const float* __restrict__ onorm, float* __restrict__ h2, int n) {
    const int lane = threadIdx.x & 63;
    const int wid = __builtin_amdgcn_readfirstlane(threadIdx.x >> 6);
    const int rowBase = (blockIdx.x * 4 + wid) * 8;
    const int cl = lane < 40 ? lane : 39;

    float w[64];
#pragma unroll
    for (int k = 0; k < 64; ++k) w[k] = W2[k * 40 + cl];

    float c2 = 0.f;
#pragma unroll
    for (int k = 0; k < 64; ++k) c2 += b1[k] * w[k];

#pragma unroll
    for (int r = 0; r < 8; ++r) {
        int row = rowBase + r;
        if (row < n) {
            const float* ar = agg + (size_t)row * 64;   // uniform -> s_load
            float acc = 0.f;
#pragma unroll
            for (int k = 0; k < 64; ++k) acc += ar[k] * w[k];
            float so = onorm[row];
            float s12 = inorm[row] * so;
            if (lane < 40) h2[(size_t)row * 40 + lane] = acc * s12 + so * c2;
        }
    }
}

// ---------------- agg layer2 fused: in-LDS sort + gather-acc + epilogue ----------

__global__ __launch_bounds__(1024) void agg40_fused_kernel(
    const int* __restrict__ dBase, const int* __restrict__ bsrc,
    const unsigned char* __restrict__ bdlo, const float* __restrict__ h2,
    const float* __restrict__ b2, float* __restrict__ out) {
    __shared__ int lsrc[CAP];
    __shared__ int hist[256], scn[256], cur[256];
    const int tid = threadIdx.x;
    const int b = blockIdx.x;
    const int lo = dBase[b];
    const int hi = min(dBase[b + 1], lo + CAP);
    if (tid < 256) hist[tid] = 0;
    __syncthreads();
    for (int p = lo + tid; p < hi; p += 1024) atomicAdd(&hist[bdlo[p]], 1);
    __syncthreads();
    int v = (tid < 256) ? hist[tid] : 0;
    if (tid < 256) scn[tid] = v;
    __syncthreads();
    for (int s = 1; s < 256; s <<= 1) {
        int u = 0;
        if (tid < 256 && tid >= s) u = scn[tid - s];
        __syncthreads();
        if (tid < 256 && tid >= s) scn[tid] += u;
        __syncthreads();
    }
    if (tid < 256) {
        int excl = scn[tid] - v;
        scn[tid] = excl;
        cur[tid] = excl;
    }
    __syncthreads();
    for (int p = lo + tid; p < hi; p += 1024) {
        int pos = atomicAdd(&cur[bdlo[p]], 1);   // LDS atomic
        lsrc[pos] = bsrc[p];
    }
    __syncthreads();

    const int w = tid >> 6, lane = tid & 63, q = lane >> 4, f = lane & 15;
    const bool act = (f < 10);
    float4 vb = make_float4(0.f, 0.f, 0.f, 0.f);
    if (act) vb = ((const float4*)b2)[f];
    for (int nn = w; nn < 256; nn += 16) {
        int node = b * 256 + nn;
        if (node >= N_NODES) break;
        int beg = scn[nn];
        int end = beg + hist[nn];
        float4 a0 = {0.f, 0.f, 0.f, 0.f}, a1 = {0.f, 0.f, 0.f, 0.f};
        int j = beg;
        for (; j + 8 <= end; j += 8) {
            int s0 = lsrc[j + q], s1 = lsrc[j + 4 + q];
            if (act) {
                float4 v0 = *((const float4*)(h2 + (size_t)s0 * 40) + f);
                float4 v1 = *((const float4*)(h2 + (size_t)s1 * 40) + f);
                a0.x += v0.x; a0.y += v0.y; a0.z += v0.z; a0.w += v0.w;
                a1.x += v1.x; a1.y += v1.y; a1.z += v1.z; a1.w += v1.w;
            }
        }
        for (; j + 4 <= end; j += 4) {
            int s0 = lsrc[j + q];
            if (act) {
                float4 v0 = *((const float4*)(h2 + (size_t)s0 * 40) + f);
                a0.x += v0.x; a0.y += v0.y; a0.z += v0.z; a0.w += v0.w;
            }
        }
        if (j + q < end && act) {
            int s0 = lsrc[j + q];
            float4 v0 = *((const float4*)(h2 + (size_t)s0 * 40) + f);
            a0.x += v0.x; a0.y += v0.y; a0.z += v0.z; a0.w += v0.w;
        }
        a0.x += a1.x; a0.y += a1.y; a0.z += a1.z; a0.w += a1.w;
        a0.x += __shfl_xor(a0.x, 16); a0.y += __shfl_xor(a0.y, 16);
        a0.z += __shfl_xor(a0.z, 16); a0.w += __shfl_xor(a0.w, 16);
        a0.x += __shfl_xor(a0.x, 32); a0.y += __shfl_xor(a0.y, 32);
        a0.z += __shfl_xor(a0.z, 32); a0.w += __shfl_xor(a0.w, 32);
        if (q == 0 && act) {
            float s = 1.0f / sqrtf((float)max(hist[nn], 1));
            float4 r;
            r.x = a0.x * s + vb.x; r.y = a0.y * s + vb.y;
            r.z = a0.z * s + vb.z; r.w = a0.w * s + vb.w;
            ((float4*)(out + (size_t)node * 40))[f] = r;
        }
    }
}

extern "C" void kernel_launch(void* const* d_in, const int* in_sizes, int n_in,
                              void* d_out, int out_size, void* d_ws, size_t ws_size,
                              hipStream_t stream) {
    const float* x  = (const float*)d_in[0];
    const int* src  = (const int*)d_in[1];
    const int* dst  = (const int*)d_in[2];
    const float* W1 = (const float*)d_in[3];
    const float* b1 = (const float*)d_in[4];
    const float* W2 = (const float*)d_in[5];
    const float* b2 = (const float*)d_in[6];
    float* out = (float*)d_out;

    char* wsb = (char*)d_ws;
    size_t off = 0;
    auto alloc = [&](size_t bytes) { char* p = wsb + off; off += (bytes + 255) & ~size_t(255); return p; };

    int*   zeroed = (int*)  alloc(4 * NBUCK * 4);        // gHD | gHS | dRes | sRes
    int*   gHD    = zeroed;
    int*   gHS    = zeroed + NBUCK;
    int*   dRes   = zeroed + 2 * NBUCK;
    int*   sRes   = zeroed + 3 * NBUCK;
    int*   dBase  = (int*)  alloc((NBUCK + 1) * 4);
    int*   sBase  = (int*)  alloc((NBUCK + 1) * 4);
    float* onorm  = (float*)alloc(N_NODES * 4);
    float* inorm  = (float*)alloc(N_NODES * 4);
    int*   bsrc   = (int*)  alloc((size_t)N_EDGES * 4);
    unsigned char* bdlo = (unsigned char*)alloc(N_EDGES);
    unsigned char* bslo = (unsigned char*)alloc(N_EDGES);
    float* h1     = (float*)alloc((size_t)N_NODES * 64 * 4);  // reused as h2 (N*40)
    float* agg1   = (float*)alloc((size_t)N_NODES * 64 * 4);
    float* h2 = h1;

    hipMemsetAsync(zeroed, 0, 4 * NBUCK * 4, stream);

    coarse_hist_kernel<<<HBLK, 256, 0, stream>>>(src, dst, gHD, gHS);
    coarse_scan_kernel<<<1, 512, 0, stream>>>(gHD, gHS, dBase, sBase);
    scatter_both_kernel<<<HBLK, 256, 0, stream>>>(src, dst, dBase, sBase, dRes, sRes,
                                                  bsrc, bdlo, bslo);
    fine_src_kernel<<<NBUCK, 256, 0, stream>>>(sBase, bslo, onorm);

    gemm1_kernel<<<(N_NODES + 127) / 128, 256, 0, stream>>>(x, W1, onorm, h1, N_NODES);

    agg64_fused_kernel<<<NBUCK, 1024, 0, stream>>>(dBase, bsrc, bdlo, h1, agg1, inorm);

    gemm2_kernel<<<(N_NODES + 31) / 32, 256, 0, stream>>>(agg1, W2, b1, inorm, onorm, h2, N_NODES);

    agg40_fused_kernel<<<NBUCK, 1024, 0, stream>>>(dBase, bsrc, bdlo, h2, b2, out);
}

// Round 7
// 432.837 us; speedup vs baseline: 2.1781x; 1.0106x over previous
//
#include <hip/hip_runtime.h>

#define N_NODES 100000
#define N_EDGES 1600000
#define BSH 7                // bucket shift: 128 nodes per bucket
#define NBUCK 782            // ceil(N_NODES / 128)
#define BMASK 127
#define HBLK 512             // blocks for histogram/scatter kernels
#define CAP 4096             // LDS edge-list capacity per bucket (mean 2048, sd 45)

// ---------------- K1: coarse histograms of dst>>7 and src>>7 ----------------

__global__ __launch_bounds__(256) void coarse_hist_kernel(
    const int* __restrict__ src, const int* __restrict__ dst,
    int* __restrict__ gHD, int* __restrict__ gHS) {
    __shared__ int hd[NBUCK], hs[NBUCK];
    for (int i = threadIdx.x; i < NBUCK; i += 256) { hd[i] = 0; hs[i] = 0; }
    __syncthreads();
    for (int e = blockIdx.x * 256 + threadIdx.x; e < N_EDGES; e += HBLK * 256) {
        atomicAdd(&hd[dst[e] >> BSH], 1);
        atomicAdd(&hs[src[e] >> BSH], 1);
    }
    __syncthreads();
    for (int i = threadIdx.x; i < NBUCK; i += 256) {
        if (hd[i]) atomicAdd(&gHD[i], hd[i]);
        if (hs[i]) atomicAdd(&gHS[i], hs[i]);
    }
}

// ---------------- K2: scan coarse bins -> bucket bases ----------------

__global__ __launch_bounds__(1024) void coarse_scan_kernel(
    const int* __restrict__ gHD, const int* __restrict__ gHS,
    int* __restrict__ dBase, int* __restrict__ sBase) {
    __shared__ int sd[1024], se[1024];
    int t = threadIdx.x;
    int vd = (t < NBUCK) ? gHD[t] : 0;
    int vs = (t < NBUCK) ? gHS[t] : 0;
    sd[t] = vd; se[t] = vs;
    __syncthreads();
    for (int s = 1; s < 1024; s <<= 1) {
        int ud = (t >= s) ? sd[t - s] : 0;
        int us = (t >= s) ? se[t - s] : 0;
        __syncthreads();
        sd[t] += ud; se[t] += us;
        __syncthreads();
    }
    if (t < NBUCK) { dBase[t] = sd[t] - vd; sBase[t] = se[t] - vs; }
    if (t == 0) { dBase[NBUCK] = N_EDGES; sBase[NBUCK] = N_EDGES; }
}

// ---------------- K3: merged scatter into dst-buckets AND src-buckets ----------------
// dst-bucket entry packed: (src << 7) | (dst & 127)   (src < 2^17 -> 24 bits)

__global__ __launch_bounds__(256) void scatter_both_kernel(
    const int* __restrict__ src, const int* __restrict__ dst,
    const int* __restrict__ dBase, const int* __restrict__ sBase,
    int* __restrict__ dRes, int* __restrict__ sRes,
    int* __restrict__ bpack, unsigned char* __restrict__ bslo) {
    __shared__ int hd[NBUCK], hs[NBUCK], curD[NBUCK], curS[NBUCK];
    for (int i = threadIdx.x; i < NBUCK; i += 256) { hd[i] = 0; hs[i] = 0; }
    __syncthreads();
    for (int e = blockIdx.x * 256 + threadIdx.x; e < N_EDGES; e += HBLK * 256) {
        atomicAdd(&hd[dst[e] >> BSH], 1);
        atomicAdd(&hs[src[e] >> BSH], 1);
    }
    __syncthreads();
    for (int i = threadIdx.x; i < NBUCK; i += 256) {
        int cd = hd[i];
        curD[i] = dBase[i] + (cd ? atomicAdd(&dRes[i], cd) : 0);
        int cs = hs[i];
        curS[i] = sBase[i] + (cs ? atomicAdd(&sRes[i], cs) : 0);
    }
    __syncthreads();
    for (int e = blockIdx.x * 256 + threadIdx.x; e < N_EDGES; e += HBLK * 256) {
        int s = src[e];
        int d = dst[e];
        int pd = atomicAdd(&curD[d >> BSH], 1);   // LDS atomic
        bpack[pd] = (s << BSH) | (d & BMASK);
        int ps = atomicAdd(&curS[s >> BSH], 1);   // LDS atomic
        bslo[ps] = (unsigned char)(s & BMASK);
    }
}

// ---------------- K4: fine per src-bucket: odeg -> onorm ----------------

__global__ __launch_bounds__(256) void fine_src_kernel(
    const int* __restrict__ sBase, const unsigned char* __restrict__ bslo,
    float* __restrict__ onorm) {
    __shared__ int hist[128];
    int t = threadIdx.x, b = blockIdx.x;
    int lo = sBase[b], hi = sBase[b + 1];
    if (t < 128) hist[t] = 0;
    __syncthreads();
    for (int p = lo + t; p < hi; p += 256) atomicAdd(&hist[bslo[p]], 1);
    __syncthreads();
    int node = b * 128 + t;
    if (t < 128 && node < N_NODES) onorm[node] = 1.0f / sqrtf((float)max(hist[t], 1));
}

// ---------------- GEMM1: h1 = (x @ W1) * out_norm   [N,256]@[256,64] ----------------
// 128x64 tile, 128 threads, 8x8 micro-tile, register-double-buffered staging.
// (R6 post-mortem: LDS-read-throughput bound; 8x8 halves LDS bytes/FLOP.)

__global__ __launch_bounds__(128) void gemm1_kernel(
    const float* __restrict__ x, const float* __restrict__ W,
    const float* __restrict__ onorm, float* __restrict__ h, int n) {
    __shared__ float As[16][128];   // [k][row]
    __shared__ float Ws[16][68];    // [k][col], padded
    const int tid = threadIdx.x;
    const int tx = tid & 7;         // col group (8 cols)
    const int ry = tid >> 3;        // row group (8 rows)
    const int rowBase = blockIdx.x * 128;

    const int lr = tid >> 2;        // 0..31 (4 passes of 32 rows)
    const int kq = (tid & 3) * 4;   // 0,4,8,12
    const int wk = tid >> 3;        // 0..15
    const int wc = (tid & 7) * 8;   // 0..56

    float4 va[4], vw0, vw1;

    auto load_regs = [&](int k0) {
#pragma unroll
        for (int p = 0; p < 4; ++p) {
            int row = rowBase + p * 32 + lr;
            va[p] = (row < n) ? *(const float4*)(x + (size_t)row * 256 + k0 + kq)
                              : make_float4(0.f, 0.f, 0.f, 0.f);
        }
        vw0 = *(const float4*)(W + (size_t)wk * 64 + wc);
        vw1 = *(const float4*)(W + (size_t)wk * 64 + wc + 4);
    };
    auto load_regs_w = [&](int k0) {
#pragma unroll
        for (int p = 0; p < 4; ++p) {
            int row = rowBase + p * 32 + lr;
            va[p] = (row < n) ? *(const float4*)(x + (size_t)row * 256 + k0 + kq)
                              : make_float4(0.f, 0.f, 0.f, 0.f);
        }
        vw0 = *(const float4*)(W + (size_t)(k0 + wk) * 64 + wc);
        vw1 = *(const float4*)(W + (size_t)(k0 + wk) * 64 + wc + 4);
    };

    float acc[8][8] = {};

    load_regs(0);
    for (int k0 = 0; k0 < 256; k0 += 16) {
        // store staged regs to LDS
#pragma unroll
        for (int p = 0; p < 4; ++p) {
            int r = p * 32 + lr;
            As[kq + 0][r] = va[p].x;
            As[kq + 1][r] = va[p].y;
            As[kq + 2][r] = va[p].z;
            As[kq + 3][r] = va[p].w;
        }
        *(float4*)&Ws[wk][wc] = vw0;
        *(float4*)&Ws[wk][wc + 4] = vw1;
        __syncthreads();
        if (k0 + 16 < 256) load_regs_w(k0 + 16);   // prefetch next chunk (in flight during compute)
#pragma unroll
        for (int k = 0; k < 16; ++k) {
            float4 b0 = *(const float4*)&Ws[k][tx * 8];
            float4 b1 = *(const float4*)&Ws[k][tx * 8 + 4];
            float4 a0 = *(const float4*)&As[k][ry * 8];
            float4 a1 = *(const float4*)&As[k][ry * 8 + 4];
            float av[8] = {a0.x, a0.y, a0.z, a0.w, a1.x, a1.y, a1.z, a1.w};
            float bv[8] = {b0.x, b0.y, b0.z, b0.w, b1.x, b1.y, b1.z, b1.w};
#pragma unroll
            for (int i = 0; i < 8; ++i)
#pragma unroll
                for (int j = 0; j < 8; ++j) acc[i][j] += av[i] * bv[j];
        }
        __syncthreads();
    }
#pragma unroll
    for (int i = 0; i < 8; ++i) {
        int row = rowBase + ry * 8 + i;
        if (row < n) {
            float s = onorm[row];
            *(float4*)(h + (size_t)row * 64 + tx * 8) =
                make_float4(acc[i][0] * s, acc[i][1] * s, acc[i][2] * s, acc[i][3] * s);
            *(float4*)(h + (size_t)row * 64 + tx * 8 + 4) =
                make_float4(acc[i][4] * s, acc[i][5] * s, acc[i][6] * s, acc[i][7] * s);
        }
    }
}

// ---------------- agg layer1 fused: in-LDS bucket sort + gather-acc + inorm ----------

__global__ __launch_bounds__(512) void agg64_fused_kernel(
    const int* __restrict__ dBase, const int* __restrict__ bpack,
    const float* __restrict__ h, float* __restrict__ agg, float* __restrict__ inorm) {
    __shared__ int lsrc[CAP];
    __shared__ int hist[128], scn[128], cur[128];
    const int tid = threadIdx.x;
    const int b = blockIdx.x;
    const int lo = dBase[b];
    const int hi = min(dBase[b + 1], lo + CAP);
    if (tid < 128) hist[tid] = 0;
    __syncthreads();
    for (int p = lo + tid; p < hi; p += 512) atomicAdd(&hist[bpack[p] & BMASK], 1);
    __syncthreads();
    int v = (tid < 128) ? hist[tid] : 0;
    if (tid < 128) scn[tid] = v;
    __syncthreads();
    for (int s = 1; s < 128; s <<= 1) {
        int u = 0;
        if (tid < 128 && tid >= s) u = scn[tid - s];
        __syncthreads();
        if (tid < 128 && tid >= s) scn[tid] += u;
        __syncthreads();
    }
    if (tid < 128) {
        int excl = scn[tid] - v;
        scn[tid] = excl;
        cur[tid] = excl;
        int node = b * 128 + tid;
        if (node < N_NODES) inorm[node] = 1.0f / sqrtf((float)max(v, 1));
    }
    __syncthreads();
    for (int p = lo + tid; p < hi; p += 512) {
        int pk = bpack[p];
        int pos = atomicAdd(&cur[pk & BMASK], 1);   // LDS atomic
        lsrc[pos] = pk >> BSH;
    }
    __syncthreads();

    const int w = tid >> 6, lane = tid & 63, q = lane >> 4, f = lane & 15;
    for (int nn = w; nn < 128; nn += 8) {
        int node = b * 128 + nn;
        if (node >= N_NODES) break;
        int beg = scn[nn];
        int end = beg + hist[nn];
        float4 a0 = {0.f, 0.f, 0.f, 0.f}, a1 = {0.f, 0.f, 0.f, 0.f};
        int j = beg;
        for (; j + 8 <= end; j += 8) {
            int s0 = lsrc[j + q], s1 = lsrc[j + 4 + q];
            float4 v0 = *((const float4*)(h + (size_t)s0 * 64) + f);
            float4 v1 = *((const float4*)(h + (size_t)s1 * 64) + f);
            a0.x += v0.x; a0.y += v0.y; a0.z += v0.z; a0.w += v0.w;
            a1.x += v1.x; a1.y += v1.y; a1.z += v1.z; a1.w += v1.w;
        }
        for (; j + 4 <= end; j += 4) {
            int s0 = lsrc[j + q];
            float4 v0 = *((const float4*)(h + (size_t)s0 * 64) + f);
            a0.x += v0.x; a0.y += v0.y; a0.z += v0.z; a0.w += v0.w;
        }
        if (j + q < end) {
            int s0 = lsrc[j + q];
            float4 v0 = *((const float4*)(h + (size_t)s0 * 64) + f);
            a0.x += v0.x; a0.y += v0.y; a0.z += v0.z; a0.w += v0.w;
        }
        a0.x += a1.x; a0.y += a1.y; a0.z += a1.z; a0.w += a1.w;
        a0.x += __shfl_xor(a0.x, 16); a0.y += __shfl_xor(a0.y, 16);
        a0.z += __shfl_xor(a0.z, 16); a0.w += __shfl_xor(a0.w, 16);
        a0.x += __shfl_xor(a0.x, 32); a0.y += __shfl_xor(a0.y, 32);
        a0.z += __shfl_xor(a0.z, 32); a0.w += __shfl_xor(a0.w, 32);
        if (q == 0) ((float4*)(agg + (size_t)node * 64))[f] = a0;
    }
}

// ---------------- GEMM2: h2 = ((agg*in_norm + b1) * out_norm) @ W2  [N,64]@[64,40] ----
// Scalar-pipe outer product (validated win in R4).

__global__ __launch_bounds__(256) void gemm2_kernel(
    const float* __restrict__ agg, const float* __restrict__ W2,
    const float* __restrict__ b1, const float* __restrict__ inorm,
    const float* __restrict__ onorm, float* __restrict__ h2, int n) {
    const int lane = threadIdx.x & 63;
    const int wid = __builtin_amdgcn_readfirstlane(threadIdx.x >> 6);
    const int rowBase = (blockIdx.x * 4 + wid) * 8;
    const int cl = lane < 40 ? lane : 39;

    float w[64];
#pragma unroll
    for (int k = 0; k < 64; ++k) w[k] = W2[k * 40 + cl];

    float c2 = 0.f;
#pragma unroll
    for (int k = 0; k < 64; ++k) c2 += b1[k] * w[k];

#pragma unroll
    for (int r = 0; r < 8; ++r) {
        int row = rowBase + r;
        if (row < n) {
            const float* ar = agg + (size_t)row * 64;   // uniform -> s_load
            float acc = 0.f;
#pragma unroll
            for (int k = 0; k < 64; ++k) acc += ar[k] * w[k];
            float so = onorm[row];
            float s12 = inorm[row] * so;
            if (lane < 40) h2[(size_t)row * 40 + lane] = acc * s12 + so * c2;
        }
    }
}

// ---------------- agg layer2 fused: in-LDS sort + gather-acc + epilogue ----------

__global__ __launch_bounds__(512) void agg40_fused_kernel(
    const int* __restrict__ dBase, const int* __restrict__ bpack,
    const float* __restrict__ h2, const float* __restrict__ b2,
    float* __restrict__ out) {
    __shared__ int lsrc[CAP];
    __shared__ int hist[128], scn[128], cur[128];
    const int tid = threadIdx.x;
    const int b = blockIdx.x;
    const int lo = dBase[b];
    const int hi = min(dBase[b + 1], lo + CAP);
    if (tid < 128) hist[tid] = 0;
    __syncthreads();
    for (int p = lo + tid; p < hi; p += 512) atomicAdd(&hist[bpack[p] & BMASK], 1);
    __syncthreads();
    int v = (tid < 128) ? hist[tid] : 0;
    if (tid < 128) scn[tid] = v;
    __syncthreads();
    for (int s = 1; s < 128; s <<= 1) {
        int u = 0;
        if (tid < 128 && tid >= s) u = scn[tid - s];
        __syncthreads();
        if (tid < 128 && tid >= s) scn[tid] += u;
        __syncthreads();
    }
    if (tid < 128) {
        int excl = scn[tid] - v;
        scn[tid] = excl;
        cur[tid] = excl;
    }
    __syncthreads();
    for (int p = lo + tid; p < hi; p += 512) {
        int pk = bpack[p];
        int pos = atomicAdd(&cur[pk & BMASK], 1);   // LDS atomic
        lsrc[pos] = pk >> BSH;
    }
    __syncthreads();

    const int w = tid >> 6, lane = tid & 63, q = lane >> 4, f = lane & 15;
    const bool act = (f < 10);
    float4 vb = make_float4(0.f, 0.f, 0.f, 0.f);
    if (act) vb = ((const float4*)b2)[f];
    for (int nn = w; nn < 128; nn += 8) {
        int node = b * 128 + nn;
        if (node >= N_NODES) break;
        int beg = scn[nn];
        int end = beg + hist[nn];
        float4 a0 = {0.f, 0.f, 0.f, 0.f}, a1 = {0.f, 0.f, 0.f, 0.f};
        int j = beg;
        for (; j + 8 <= end; j += 8) {
            int s0 = lsrc[j + q], s1 = lsrc[j + 4 + q];
            if (act) {
                float4 v0 = *((const float4*)(h2 + (size_t)s0 * 40) + f);
                float4 v1 = *((const float4*)(h2 + (size_t)s1 * 40) + f);
                a0.x += v0.x; a0.y += v0.y; a0.z += v0.z; a0.w += v0.w;
                a1.x += v1.x; a1.y += v1.y; a1.z += v1.z; a1.w += v1.w;
            }
        }
        for (; j + 4 <= end; j += 4) {
            int s0 = lsrc[j + q];
            if (act) {
                float4 v0 = *((const float4*)(h2 + (size_t)s0 * 40) + f);
                a0.x += v0.x; a0.y += v0.y; a0.z += v0.z; a0.w += v0.w;
            }
        }
        if (j + q < end && act) {
            int s0 = lsrc[j + q];
            float4 v0 = *((const float4*)(h2 + (size_t)s0 * 40) + f);
            a0.x += v0.x; a0.y += v0.y; a0.z += v0.z; a0.w += v0.w;
        }
        a0.x += a1.x; a0.y += a1.y; a0.z += a1.z; a0.w += a1.w;
        a0.x += __shfl_xor(a0.x, 16); a0.y += __shfl_xor(a0.y, 16);
        a0.z += __shfl_xor(a0.z, 16); a0.w += __shfl_xor(a0.w, 16);
        a0.x += __shfl_xor(a0.x, 32); a0.y += __shfl_xor(a0.y, 32);
        a0.z += __shfl_xor(a0.z, 32); a0.w += __shfl_xor(a0.w, 32);
        if (q == 0 && act) {
            float s = 1.0f / sqrtf((float)max(hist[nn], 1));
            float4 r;
            r.x = a0.x * s + vb.x; r.y = a0.y * s + vb.y;
            r.z = a0.z * s + vb.z; r.w = a0.w * s + vb.w;
            ((float4*)(out + (size_t)node * 40))[f] = r;
        }
    }
}

extern "C" void kernel_launch(void* const* d_in, const int* in_sizes, int n_in,
                              void* d_out, int out_size, void* d_ws, size_t ws_size,
                              hipStream_t stream) {
    const float* x  = (const float*)d_in[0];
    const int* src  = (const int*)d_in[1];
    const int* dst  = (const int*)d_in[2];
    const float* W1 = (const float*)d_in[3];
    const float* b1 = (const float*)d_in[4];
    const float* W2 = (const float*)d_in[5];
    const float* b2 = (const float*)d_in[6];
    float* out = (float*)d_out;

    char* wsb = (char*)d_ws;
    size_t off = 0;
    auto alloc = [&](size_t bytes) { char* p = wsb + off; off += (bytes + 255) & ~size_t(255); return p; };

    int*   zeroed = (int*)  alloc(4 * NBUCK * 4);        // gHD | gHS | dRes | sRes
    int*   gHD    = zeroed;
    int*   gHS    = zeroed + NBUCK;
    int*   dRes   = zeroed + 2 * NBUCK;
    int*   sRes   = zeroed + 3 * NBUCK;
    int*   dBase  = (int*)  alloc((NBUCK + 1) * 4);
    int*   sBase  = (int*)  alloc((NBUCK + 1) * 4);
    float* onorm  = (float*)alloc(N_NODES * 4);
    float* inorm  = (float*)alloc(N_NODES * 4);
    int*   bpack  = (int*)  alloc((size_t)N_EDGES * 4);
    unsigned char* bslo = (unsigned char*)alloc(N_EDGES);
    float* h1     = (float*)alloc((size_t)N_NODES * 64 * 4);  // reused as h2 (N*40)
    float* agg1   = (float*)alloc((size_t)N_NODES * 64 * 4);
    float* h2 = h1;

    hipMemsetAsync(zeroed, 0, 4 * NBUCK * 4, stream);

    coarse_hist_kernel<<<HBLK, 256, 0, stream>>>(src, dst, gHD, gHS);
    coarse_scan_kernel<<<1, 1024, 0, stream>>>(gHD, gHS, dBase, sBase);
    scatter_both_kernel<<<HBLK, 256, 0, stream>>>(src, dst, dBase, sBase, dRes, sRes,
                                                  bpack, bslo);
    fine_src_kernel<<<NBUCK, 256, 0, stream>>>(sBase, bslo, onorm);

    gemm1_kernel<<<(N_NODES + 127) / 128, 128, 0, stream>>>(x, W1, onorm, h1, N_NODES);

    agg64_fused_kernel<<<NBUCK, 512, 0, stream>>>(dBase, bpack, h1, agg1, inorm);

    gemm2_kernel<<<(N_NODES + 31) / 32, 256, 0, stream>>>(agg1, W2, b1, inorm, onorm, h2, N_NODES);

    agg40_fused_kernel<<<NBUCK, 512, 0, stream>>>(dBase, bpack, h2, b2, out);
}